// Round 1
// baseline (2534.166 us; speedup 1.0000x reference)
//
#include <hip/hip_runtime.h>
#include <cstddef>

#define BATCH 2048
#define DM 2048
#define DI 4096
#define DS 16
#define LN_EPS 1e-5f

// ---------------- LayerNorm: one block per row ----------------
__global__ __launch_bounds__(256) void ln_kernel(const float* __restrict__ x,
                                                 const float* __restrict__ gamma,
                                                 const float* __restrict__ beta,
                                                 float* __restrict__ xn) {
  int row = blockIdx.x;
  int t = threadIdx.x;
  const float4* xr = (const float4*)(x + (size_t)row * DM);
  float4 v0 = xr[t];
  float4 v1 = xr[t + 256];
  float s  = v0.x + v0.y + v0.z + v0.w + v1.x + v1.y + v1.z + v1.w;
  float ss = v0.x*v0.x + v0.y*v0.y + v0.z*v0.z + v0.w*v0.w
           + v1.x*v1.x + v1.y*v1.y + v1.z*v1.z + v1.w*v1.w;
#pragma unroll
  for (int off = 32; off >= 1; off >>= 1) {
    s  += __shfl_down(s, off);
    ss += __shfl_down(ss, off);
  }
  __shared__ float red[8];
  int wave = t >> 6;
  if ((t & 63) == 0) { red[wave] = s; red[4 + wave] = ss; }
  __syncthreads();
  if (t == 0) {
    float fs  = red[0] + red[1] + red[2] + red[3];
    float fss = red[4] + red[5] + red[6] + red[7];
    float mu  = fs * (1.0f / DM);
    red[0] = mu;
    red[1] = rsqrtf(fss * (1.0f / DM) - mu * mu + LN_EPS);
  }
  __syncthreads();
  float mu = red[0], rstd = red[1];
  const float4* g  = (const float4*)gamma;
  const float4* be = (const float4*)beta;
  float4 g0 = g[t], g1 = g[t + 256], b0 = be[t], b1 = be[t + 256];
  float4 o0, o1;
  o0.x = (v0.x - mu) * rstd * g0.x + b0.x;
  o0.y = (v0.y - mu) * rstd * g0.y + b0.y;
  o0.z = (v0.z - mu) * rstd * g0.z + b0.z;
  o0.w = (v0.w - mu) * rstd * g0.w + b0.w;
  o1.x = (v1.x - mu) * rstd * g1.x + b1.x;
  o1.y = (v1.y - mu) * rstd * g1.y + b1.y;
  o1.z = (v1.z - mu) * rstd * g1.z + b1.z;
  o1.w = (v1.w - mu) * rstd * g1.w + b1.w;
  float4* o = (float4*)(xn + (size_t)row * DM);
  o[t] = o0;
  o[t + 256] = o1;
}

// ---------------- fp32 tiled GEMM:  C[m,n] = sum_k A[m,k]*B[n,k] (+resid) ---
// A: MxK row-major, B: NxK row-major. 64x64 tile, BK=16, 4x4 per thread.
__global__ __launch_bounds__(256) void gemm_nt(const float* __restrict__ A,
                                               const float* __restrict__ B,
                                               float* __restrict__ C,
                                               const float* __restrict__ resid,
                                               int M, int N, int K) {
  __shared__ float As[16][68];
  __shared__ float Bs[16][68];
  int t  = threadIdx.x;
  int tx = t & 15, ty = t >> 4;
  int bm = blockIdx.y << 6, bn = blockIdx.x << 6;
  int lr = t >> 2;          // 0..63 tile row
  int lk = (t & 3) << 2;    // 0,4,8,12
  const float* Ap = A + (size_t)(bm + lr) * K + lk;
  const float* Bp = B + (size_t)(bn + lr) * K + lk;
  float acc[4][4] = {};
  for (int k0 = 0; k0 < K; k0 += 16) {
    float4 av = *(const float4*)(Ap + k0);
    float4 bv = *(const float4*)(Bp + k0);
    __syncthreads();
    As[lk + 0][lr] = av.x; As[lk + 1][lr] = av.y;
    As[lk + 2][lr] = av.z; As[lk + 3][lr] = av.w;
    Bs[lk + 0][lr] = bv.x; Bs[lk + 1][lr] = bv.y;
    Bs[lk + 2][lr] = bv.z; Bs[lk + 3][lr] = bv.w;
    __syncthreads();
#pragma unroll
    for (int k = 0; k < 16; ++k) {
      float a[4], b[4];
#pragma unroll
      for (int i = 0; i < 4; ++i) a[i] = As[k][(ty << 2) + i];
#pragma unroll
      for (int j = 0; j < 4; ++j) b[j] = Bs[k][(tx << 2) + j];
#pragma unroll
      for (int i = 0; i < 4; ++i)
#pragma unroll
        for (int j = 0; j < 4; ++j)
          acc[i][j] = fmaf(a[i], b[j], acc[i][j]);
    }
  }
#pragma unroll
  for (int i = 0; i < 4; ++i) {
    int row = bm + (ty << 2) + i;
    size_t off = (size_t)row * N + bn + (tx << 2);
    float4 v = {acc[i][0], acc[i][1], acc[i][2], acc[i][3]};
    if (resid) {
      float4 r = *(const float4*)(resid + off);
      v.x += r.x; v.y += r.y; v.z += r.z; v.w += r.w;
    }
    *(float4*)(C + off) = v;
  }
}

// ---------------- xp = x_main @ W_xp.T : (B, 33), K = DI ----------------
__global__ __launch_bounds__(256) void xp_kernel(const float* __restrict__ xz,
                                                 const float* __restrict__ W_xp,
                                                 float* __restrict__ xp) {
  int b = blockIdx.x;
  int t = threadIdx.x;
  const float* xm = xz + ((size_t)b << 13);  // x_main = xz[b, 0:4096]
  float acc[33];
#pragma unroll
  for (int j = 0; j < 33; ++j) acc[j] = 0.f;
  for (int k = t; k < DI; k += 256) {
    float xv = xm[k];
#pragma unroll
    for (int j = 0; j < 33; ++j)
      acc[j] = fmaf(xv, W_xp[j * DI + k], acc[j]);
  }
#pragma unroll
  for (int j = 0; j < 33; ++j) {
#pragma unroll
    for (int off = 32; off >= 1; off >>= 1)
      acc[j] += __shfl_down(acc[j], off);
  }
  __shared__ float red[4][33];
  int wave = t >> 6, lane = t & 63;
  if (lane == 0) {
#pragma unroll
    for (int j = 0; j < 33; ++j) red[wave][j] = acc[j];
  }
  __syncthreads();
  if (t < 33)
    xp[b * 33 + t] = red[0][t] + red[1][t] + red[2][t] + red[3][t];
}

// ---------------- SSM state update + gate, thread per (b,d) ----------------
__global__ __launch_bounds__(256) void ssm_kernel(const float* __restrict__ xz,
                                                  const float* __restrict__ xp,
                                                  const float* __restrict__ h,
                                                  const float* __restrict__ log_A,
                                                  const float* __restrict__ dt_bias,
                                                  const float* __restrict__ D_param,
                                                  float* __restrict__ h_new,
                                                  float* __restrict__ y_gated) {
  size_t idx = (size_t)blockIdx.x * 256 + threadIdx.x;  // b*DI + d
  int b = (int)(idx >> 12);
  int d = (int)(idx & 4095);
  const float* xrow = xz + ((size_t)b << 13);
  float xm = xrow[d];
  float zv = xrow[4096 + d];
  const float* xpb = xp + b * 33;
  float tt = xpb[32] + dt_bias[d];
  // stable softplus
  float delta = (tt > 0.f) ? tt + log1pf(__expf(-tt)) : log1pf(__expf(tt));
  float dxm = delta * xm;
  const float4* hp  = (const float4*)(h + (idx << 4));
  const float4* lap = (const float4*)(log_A + ((size_t)d << 4));
  float4* hop = (float4*)(h_new + (idx << 4));
  float y = 0.f;
#pragma unroll
  for (int q = 0; q < 4; ++q) {
    float4 hv = hp[q];
    float4 la = lap[q];
    float B0 = xpb[q * 4 + 0], B1 = xpb[q * 4 + 1];
    float B2 = xpb[q * 4 + 2], B3 = xpb[q * 4 + 3];
    float C0 = xpb[16 + q * 4 + 0], C1 = xpb[16 + q * 4 + 1];
    float C2 = xpb[16 + q * 4 + 2], C3 = xpb[16 + q * 4 + 3];
    float4 hn;
    hn.x = __expf(-delta * __expf(la.x)) * hv.x + B0 * dxm;
    hn.y = __expf(-delta * __expf(la.y)) * hv.y + B1 * dxm;
    hn.z = __expf(-delta * __expf(la.z)) * hv.z + B2 * dxm;
    hn.w = __expf(-delta * __expf(la.w)) * hv.w + B3 * dxm;
    y = fmaf(hn.x, C0, y);
    y = fmaf(hn.y, C1, y);
    y = fmaf(hn.z, C2, y);
    y = fmaf(hn.w, C3, y);
    hop[q] = hn;
  }
  y = fmaf(D_param[d], xm, y);
  float sig = 1.0f / (1.0f + __expf(-zv));
  y_gated[idx] = y * (zv * sig);
}

extern "C" void kernel_launch(void* const* d_in, const int* in_sizes, int n_in,
                              void* d_out, int out_size, void* d_ws, size_t ws_size,
                              hipStream_t stream) {
  const float* x       = (const float*)d_in[0];
  const float* h       = (const float*)d_in[1];
  const float* W_in    = (const float*)d_in[2];
  const float* W_xp    = (const float*)d_in[3];
  const float* log_A   = (const float*)d_in[4];
  const float* dt_bias = (const float*)d_in[5];
  const float* D_param = (const float*)d_in[6];
  const float* W_out   = (const float*)d_in[7];
  const float* gamma   = (const float*)d_in[8];
  const float* beta    = (const float*)d_in[9];

  float* out   = (float*)d_out;
  float* y_out = out;                         // (BATCH, DM)
  float* h_out = out + (size_t)BATCH * DM;    // (BATCH, DI, DS)

  float* ws  = (float*)d_ws;
  float* xz  = ws;                                  // (BATCH, 2*DI) = 16.78M floats
  float* xpb = xz + (size_t)BATCH * 2 * DI;         // (BATCH, 33)
  float* yg  = xpb + (size_t)BATCH * 33;            // (BATCH, DI)  = 8.39M floats
  float* xn  = y_out;  // reuse d_out y-region as LN scratch; overwritten by GEMM2

  ln_kernel<<<BATCH, 256, 0, stream>>>(x, gamma, beta, xn);
  gemm_nt<<<dim3((2 * DI) / 64, BATCH / 64), 256, 0, stream>>>(
      xn, W_in, xz, nullptr, BATCH, 2 * DI, DM);
  xp_kernel<<<BATCH, 256, 0, stream>>>(xz, W_xp, xpb);
  ssm_kernel<<<(BATCH * DI) / 256, 256, 0, stream>>>(
      xz, xpb, h, log_A, dt_bias, D_param, h_out, yg);
  gemm_nt<<<dim3(DM / 64, BATCH / 64), 256, 0, stream>>>(
      yg, W_out, y_out, x, BATCH, DM, DI);
}